// Round 3
// baseline (737.981 us; speedup 1.0000x reference)
//
#include <hip/hip_runtime.h>
#include <math.h>

#define NB 8
#define LQ 64
#define LP 512
#define NV 32
#define DIM 512
#define NH 8
#define HD 64

typedef __attribute__((ext_vector_type(4))) float f32x4;
typedef __attribute__((ext_vector_type(8))) short s16x8;

__device__ __forceinline__ unsigned short f2bf(float x) {
  unsigned int u = __float_as_uint(x);
  u += 0x7fff + ((u >> 16) & 1);  // round-to-nearest-even
  return (unsigned short)(u >> 16);
}
__device__ __forceinline__ float bf2f(unsigned short h) {
  return __uint_as_float(((unsigned int)h) << 16);
}

// ---------------------------------------------------------------------------
// K1a: partial sums over Lp chunks + truncate-split of memory into bf16 hi/lo.
// hi = x with low 16 mantissa bits zeroed (exact); lo = x - hi (exact f32),
// truncated to bf16 -> total representation error <= 2^-16 rel.
// grid = 2048 (= 8*32 bv * 8 ch), block = 256.
// ---------------------------------------------------------------------------
__global__ __launch_bounds__(256) void k_part_split(
    const float* __restrict__ mem, float* __restrict__ part,
    unsigned short* __restrict__ memh, unsigned short* __restrict__ meml) {
  int blk = blockIdx.x;
  int bv = blk >> 3, ch = blk & 7;
  int b = bv >> 5, v = bv & 31;
  int tid = threadIdx.x;
  float a0 = 0.f, a1 = 0.f;
  int l0 = ch * 64;
  for (int l = l0; l < l0 + 64; ++l) {
    size_t base = (((size_t)b * LP + l) * NV + v) * DIM;
    float x0 = mem[base + tid];
    float x1 = mem[base + tid + 256];
    a0 += x0;
    a1 += x1;
    unsigned int u0 = __float_as_uint(x0), u1 = __float_as_uint(x1);
    unsigned short h0 = (unsigned short)(u0 >> 16);
    unsigned short h1 = (unsigned short)(u1 >> 16);
    float lo0 = x0 - __uint_as_float(u0 & 0xffff0000u);
    float lo1 = x1 - __uint_as_float(u1 & 0xffff0000u);
    memh[base + tid] = h0;
    memh[base + tid + 256] = h1;
    meml[base + tid] = (unsigned short)(__float_as_uint(lo0) >> 16);
    meml[base + tid + 256] = (unsigned short)(__float_as_uint(lo1) >> 16);
  }
  float* dst = part + ((size_t)bv * 8 + ch) * DIM;
  dst[tid] = a0;
  dst[tid + 256] = a1;
}

// K1b: reduce chunks -> mean, write split bf16 hi/lo. grid=512, block=256
__global__ __launch_bounds__(256) void k_mean_split(
    const float* __restrict__ part, unsigned short* __restrict__ mh,
    unsigned short* __restrict__ ml) {
  int o = blockIdx.x * 256 + threadIdx.x;
  int bv = o >> 9, c = o & 511;
  float s = 0.f;
#pragma unroll
  for (int ch = 0; ch < 8; ++ch) s += part[((size_t)bv * 8 + ch) * 512 + c];
  s *= (1.0f / 512.0f);
  unsigned short hh = f2bf(s);
  mh[o] = hh;
  ml[o] = f2bf(s - bf2f(hh));
}

// ---------------------------------------------------------------------------
// split a plain f32 array into bf16 hi/lo (A-operands). 8 elems/thread.
// ---------------------------------------------------------------------------
__global__ __launch_bounds__(256) void k_splitA(const float* __restrict__ src,
                                                unsigned short* __restrict__ dh,
                                                unsigned short* __restrict__ dl) {
  size_t t = (size_t)blockIdx.x * 256 + threadIdx.x;
  const float* p = src + t * 8;
  s16x8 vh, vl;
#pragma unroll
  for (int q = 0; q < 8; q += 4) {
    float4 x = *(const float4*)(p + q);
    unsigned short h0 = f2bf(x.x), h1 = f2bf(x.y), h2 = f2bf(x.z), h3 = f2bf(x.w);
    vh[q] = (short)h0; vh[q + 1] = (short)h1; vh[q + 2] = (short)h2; vh[q + 3] = (short)h3;
    vl[q] = (short)f2bf(x.x - bf2f(h0));
    vl[q + 1] = (short)f2bf(x.y - bf2f(h1));
    vl[q + 2] = (short)f2bf(x.z - bf2f(h2));
    vl[q + 3] = (short)f2bf(x.w - bf2f(h3));
  }
  *(s16x8*)(dh + t * 8) = vh;
  *(s16x8*)(dl + t * 8) = vl;
}

// ---------------------------------------------------------------------------
// split + TRANSPOSE 512x512 weights -> WT[n][k] bf16 hi/lo. grid (8,8,6).
// ---------------------------------------------------------------------------
__global__ __launch_bounds__(256) void k_splitWT(
    const float* W0, const float* W1, const float* W2, const float* W3,
    const float* W4, const float* W5, unsigned short* __restrict__ dh,
    unsigned short* __restrict__ dl) {
  __shared__ float tf[64][65];
  int z = blockIdx.z;
  const float* W = z == 0 ? W0 : z == 1 ? W1 : z == 2 ? W2 : z == 3 ? W3
                 : z == 4 ? W4 : W5;
  unsigned short* oh = dh + (size_t)z * 262144;
  unsigned short* ol = dl + (size_t)z * 262144;
  int r0 = blockIdx.x * 64, c0 = blockIdx.y * 64;
  int tid = threadIdx.x;
  int r = tid >> 2, cs = (tid & 3) * 16;
#pragma unroll
  for (int q = 0; q < 16; q += 4) {
    float4 w4 = *(const float4*)(W + (size_t)(r0 + r) * 512 + c0 + cs + q);
    tf[r][cs + q] = w4.x; tf[r][cs + q + 1] = w4.y;
    tf[r][cs + q + 2] = w4.z; tf[r][cs + q + 3] = w4.w;
  }
  __syncthreads();
  int c = tid >> 2, rs = (tid & 3) * 16;
  s16x8 vh0, vh1, vl0, vl1;
#pragma unroll
  for (int j = 0; j < 16; ++j) {
    float x = tf[rs + j][c];
    unsigned short hh = f2bf(x);
    unsigned short ll = f2bf(x - bf2f(hh));
    if (j < 8) { vh0[j] = (short)hh; vl0[j] = (short)ll; }
    else       { vh1[j - 8] = (short)hh; vl1[j - 8] = (short)ll; }
  }
  size_t off = (size_t)(c0 + c) * 512 + r0 + rs;
  *(s16x8*)(oh + off) = vh0; *(s16x8*)(oh + off + 8) = vh1;
  *(s16x8*)(ol + off) = vl0; *(s16x8*)(ol + off + 8) = vl1;
}

// ---------------------------------------------------------------------------
// Shared GEMM machinery: 64x64 tile, 4 waves of 32x32, BK=64, split-bf16
// 3-term MFMA, double-buffered LDS with register prefetch (one barrier/tile).
// ---------------------------------------------------------------------------
#define GLOAD(k0)                                \
  do {                                           \
    pf[0] = *(const s16x8*)(pAh + (k0));         \
    pf[1] = *(const s16x8*)(pAh + (k0) + 8);     \
    pf[2] = *(const s16x8*)(pAl + (k0));         \
    pf[3] = *(const s16x8*)(pAl + (k0) + 8);     \
    pf[4] = *(const s16x8*)(pBh + (k0));         \
    pf[5] = *(const s16x8*)(pBh + (k0) + 8);     \
    pf[6] = *(const s16x8*)(pBl + (k0));         \
    pf[7] = *(const s16x8*)(pBl + (k0) + 8);     \
  } while (0)

#define SWRITE(buf)                                                        \
  do {                                                                     \
    *(s16x8*)((char*)AsH[buf] + sr * 128 + (sb ^ swz)) = pf[0];            \
    *(s16x8*)((char*)AsH[buf] + sr * 128 + ((sb + 16) ^ swz)) = pf[1];     \
    *(s16x8*)((char*)AsL[buf] + sr * 128 + (sb ^ swz)) = pf[2];            \
    *(s16x8*)((char*)AsL[buf] + sr * 128 + ((sb + 16) ^ swz)) = pf[3];     \
    *(s16x8*)((char*)BsH[buf] + sr * 128 + (sb ^ swz)) = pf[4];            \
    *(s16x8*)((char*)BsH[buf] + sr * 128 + ((sb + 16) ^ swz)) = pf[5];     \
    *(s16x8*)((char*)BsL[buf] + sr * 128 + (sb ^ swz)) = pf[6];            \
    *(s16x8*)((char*)BsL[buf] + sr * 128 + ((sb + 16) ^ swz)) = pf[7];     \
  } while (0)

#define MFMA_INNER(buf)                                                       \
  do {                                                                        \
    _Pragma("unroll") for (int ks = 0; ks < 2; ++ks) {                        \
      int kb = ks * 64 + kg * 16;                                             \
      s16x8 aH[2], aL[2], bH[2], bL[2];                                       \
      _Pragma("unroll") for (int mt = 0; mt < 2; ++mt) {                      \
        int row = wm + mt * 16 + lr;                                          \
        int off = row * 128 + (kb ^ ((row & 7) << 4));                        \
        aH[mt] = *(const s16x8*)((const char*)AsH[buf] + off);                \
        aL[mt] = *(const s16x8*)((const char*)AsL[buf] + off);                \
      }                                                                       \
      _Pragma("unroll") for (int nt = 0; nt < 2; ++nt) {                      \
        int row = wn + nt * 16 + lr;                                          \
        int off = row * 128 + (kb ^ ((row & 7) << 4));                        \
        bH[nt] = *(const s16x8*)((const char*)BsH[buf] + off);                \
        bL[nt] = *(const s16x8*)((const char*)BsL[buf] + off);                \
      }                                                                       \
      _Pragma("unroll") for (int mt = 0; mt < 2; ++mt)                        \
          _Pragma("unroll") for (int nt = 0; nt < 2; ++nt) {                  \
        acc[mt][nt] = __builtin_amdgcn_mfma_f32_16x16x32_bf16(                \
            aH[mt], bH[nt], acc[mt][nt], 0, 0, 0);                            \
        acc[mt][nt] = __builtin_amdgcn_mfma_f32_16x16x32_bf16(                \
            aH[mt], bL[nt], acc[mt][nt], 0, 0, 0);                            \
        acc[mt][nt] = __builtin_amdgcn_mfma_f32_16x16x32_bf16(                \
            aL[mt], bH[nt], acc[mt][nt], 0, 0, 0);                            \
      }                                                                       \
    }                                                                         \
  } while (0)

#define GEMM_PREAMBLE()                       \
  int tid = threadIdx.x;                      \
  int lane = tid & 63, wave = tid >> 6;       \
  int wm = (wave >> 1) * 32, wn = (wave & 1) * 32; \
  int lr = lane & 15, kg = lane >> 4;         \
  int sr = tid >> 2, sb = (tid & 3) * 32;     \
  int swz = (sr & 7) << 4;                    \
  f32x4 acc[2][2] = {};                       \
  s16x8 pf[8];

// C[M x ldc] = A[M x K] @ B^T (B given [N][K]) + bias. grid (M/64, N/64).
__global__ __launch_bounds__(256) void mgemm(
    const unsigned short* __restrict__ Ahi, const unsigned short* __restrict__ Alo,
    const unsigned short* __restrict__ Bhi, const unsigned short* __restrict__ Blo,
    const float* __restrict__ bias, float* __restrict__ C, int K, int ldc) {
  __shared__ unsigned short AsH[2][4096], AsL[2][4096], BsH[2][4096], BsL[2][4096];
  GEMM_PREAMBLE();
  int m0 = blockIdx.x * 64, n0 = blockIdx.y * 64;
  const unsigned short* pAh = Ahi + (size_t)(m0 + sr) * K + (sb >> 1);
  const unsigned short* pAl = Alo + (size_t)(m0 + sr) * K + (sb >> 1);
  const unsigned short* pBh = Bhi + (size_t)(n0 + sr) * K + (sb >> 1);
  const unsigned short* pBl = Blo + (size_t)(n0 + sr) * K + (sb >> 1);
  int NT = K >> 6;
  GLOAD(0);
  SWRITE(0);
  __syncthreads();
  for (int t = 0; t < NT; ++t) {
    int cur = t & 1;
    if (t + 1 < NT) GLOAD((t + 1) * 64);
    MFMA_INNER(cur);
    if (t + 1 < NT) SWRITE(cur ^ 1);
    __syncthreads();
  }
#pragma unroll
  for (int mt = 0; mt < 2; ++mt)
#pragma unroll
    for (int nt = 0; nt < 2; ++nt) {
      int col = n0 + wn + nt * 16 + lr;
      float badd = bias ? bias[col] : 0.f;
      int rowb = m0 + wm + mt * 16 + kg * 4;
#pragma unroll
      for (int r = 0; r < 4; ++r)
        C[(size_t)(rowb + r) * ldc + col] = acc[mt][nt][r] + badd;
    }
}

// ---------------------------------------------------------------------------
// K2c: channel scores + softmax + w_sum. grid 64.
// ---------------------------------------------------------------------------
__global__ __launch_bounds__(256) void k_ch(const float* __restrict__ qlin,
                                            const float* __restrict__ kclin,
                                            float* __restrict__ wsum) {
  __shared__ float qcs[4096];
  __shared__ float kcs[2048];
  __shared__ float sc[2048];
  int bh = blockIdx.x;
  int b = bh >> 3, h = bh & 7;
  int tid = threadIdx.x;
  const float* qsrc = qlin + ((size_t)b * LQ + h * 8) * DIM;
  for (int s = tid; s < 4096; s += 256) qcs[s] = qsrc[s];
  const float* ksrc = kclin + ((size_t)b * NV + h * 4) * DIM;
  for (int s = tid; s < 2048; s += 256) kcs[s] = ksrc[s];
  __syncthreads();
  for (int s = tid; s < 2048; s += 256) {
    int q = s >> 5, v = s & 31;
    float acc = 0.f;
#pragma unroll 8
    for (int d = 0; d < 64; ++d) acc = fmaf(qcs[q * 64 + d], kcs[v * 64 + d], acc);
    sc[s] = acc * 8.0f;
  }
  __syncthreads();
  if (tid < 64) {
    int q = tid;
    float m = -INFINITY;
    for (int v = 0; v < 32; ++v) m = fmaxf(m, sc[q * 32 + v]);
    float sum = 0.f;
    for (int v = 0; v < 32; ++v) {
      float e = __expf(sc[q * 32 + v] - m);
      sc[q * 32 + v] = e;
      sum += e;
    }
    float inv = 1.0f / sum;
    for (int v = 0; v < 32; ++v) sc[q * 32 + v] *= inv;
  }
  __syncthreads();
  if (tid < 32) {
    float s = 0.f;
    for (int q = 0; q < 64; ++q) s += sc[q * 32 + tid];
    wsum[(size_t)bh * 32 + tid] = s;
  }
}

// ---------------------------------------------------------------------------
// K2d: W_effT[bh][hd][a*512+c] split bf16 (transposed). grid 256 (bh,a).
// ---------------------------------------------------------------------------
__global__ __launch_bounds__(256) void k_weff(const float* __restrict__ wsum,
                                              const float* __restrict__ Wv_c,
                                              unsigned short* __restrict__ wth,
                                              unsigned short* __restrict__ wtl) {
  __shared__ float tf[64][65];
  int bh = blockIdx.x >> 2, a = blockIdx.x & 3;
  int tid = threadIdx.x;
  float wsv[8];
#pragma unroll
  for (int r = 0; r < 8; ++r) wsv[r] = wsum[(size_t)bh * 32 + a * 8 + r];
  int cl = tid >> 2, hg = (tid & 3) * 16;
  int hd = tid >> 2, cs = (tid & 3) * 16;
  for (int c0 = 0; c0 < 512; c0 += 64) {
    float v[16] = {};
#pragma unroll
    for (int r = 0; r < 8; ++r) {
      const float* wp = Wv_c + (size_t)(c0 + cl) * 512 + r * 64 + hg;
#pragma unroll
      for (int j = 0; j < 16; j += 4) {
        float4 w4 = *(const float4*)(wp + j);
        v[j] = fmaf(wsv[r], w4.x, v[j]);
        v[j + 1] = fmaf(wsv[r], w4.y, v[j + 1]);
        v[j + 2] = fmaf(wsv[r], w4.z, v[j + 2]);
        v[j + 3] = fmaf(wsv[r], w4.w, v[j + 3]);
      }
    }
    __syncthreads();
#pragma unroll
    for (int j = 0; j < 16; ++j) tf[cl][hg + j] = v[j];
    __syncthreads();
    s16x8 vh0, vh1, vl0, vl1;
#pragma unroll
    for (int j = 0; j < 16; ++j) {
      float x = tf[cs + j][hd];
      unsigned short hh = f2bf(x);
      unsigned short ll = f2bf(x - bf2f(hh));
      if (j < 8) { vh0[j] = (short)hh; vl0[j] = (short)ll; }
      else       { vh1[j - 8] = (short)hh; vl1[j - 8] = (short)ll; }
    }
    size_t off = ((size_t)bh * 64 + hd) * 2048 + a * 512 + c0 + cs;
    *(s16x8*)(wth + off) = vh0; *(s16x8*)(wth + off + 8) = vh1;
    *(s16x8*)(wtl + off) = vl0; *(s16x8*)(wtl + off + 8) = vl1;
  }
}

// ---------------------------------------------------------------------------
// K3: stage-1 aggregation GEMM, pre-split A (memh/meml), K=2048, dbuf.
// grid 512, XCD swizzle keeps each bh's weffT slice on one XCD.
// ---------------------------------------------------------------------------
__global__ __launch_bounds__(256) void k_stage1m(
    const unsigned short* __restrict__ Amh, const unsigned short* __restrict__ Aml,
    const unsigned short* __restrict__ WTh, const unsigned short* __restrict__ WTl,
    unsigned short* __restrict__ mgh, unsigned short* __restrict__ mgl) {
  __shared__ unsigned short AsH[2][4096], AsL[2][4096], BsH[2][4096], BsL[2][4096];
  GEMM_PREAMBLE();
  int P = blockIdx.x;
  int blk = (P & 7) * 64 + (P >> 3);
  int b = blk >> 6, h = (blk >> 3) & 7, i = blk & 7;
  int bh = b * 8 + h;
  size_t arow = ((size_t)(b * 512 + h * 64 + sr) * 32 + 4 * i) * 512 + (sb >> 1);
  const unsigned short* pAh = Amh + arow;
  const unsigned short* pAl = Aml + arow;
  const unsigned short* pBh = WTh + ((size_t)bh * 64 + sr) * 2048 + (sb >> 1);
  const unsigned short* pBl = WTl + ((size_t)bh * 64 + sr) * 2048 + (sb >> 1);
  const int NT = 32;
  GLOAD(0);
  SWRITE(0);
  __syncthreads();
  for (int t = 0; t < NT; ++t) {
    int cur = t & 1;
    if (t + 1 < NT) GLOAD((t + 1) * 64);
    MFMA_INNER(cur);
    if (t + 1 < NT) SWRITE(cur ^ 1);
    __syncthreads();
  }
#pragma unroll
  for (int mt = 0; mt < 2; ++mt)
#pragma unroll
    for (int nt = 0; nt < 2; ++nt) {
      int hd = wn + nt * 16 + lr;
      int jb = wm + mt * 16 + kg * 4;
#pragma unroll
      for (int r = 0; r < 4; ++r) {
        int j = jb + r;
        size_t idx = ((size_t)b * 512 + 8 * j + i) * 512 + h * 64 + hd;
        float v = acc[mt][nt][r];
        unsigned short hh = f2bf(v);
        mgh[idx] = hh;
        mgl[idx] = f2bf(v - bf2f(hh));
      }
    }
}

// ---------------------------------------------------------------------------
// K4: stage-2 attention (f32 VALU) + split epilogue. grid 64.
// ---------------------------------------------------------------------------
__global__ __launch_bounds__(256) void k_attn(const float* __restrict__ q2,
                                              const float* __restrict__ kmat,
                                              const float* __restrict__ vmat,
                                              unsigned short* __restrict__ ath,
                                              unsigned short* __restrict__ atl) {
  __shared__ float Qs[4096];
  __shared__ float Ks[4096];
  __shared__ float Vs[4096];
  int bh = blockIdx.x;
  int b = bh >> 3, h = bh & 7;
  int tid = threadIdx.x;
  for (int s = tid; s < 4096; s += 256) {
    int q = s >> 6, hd = s & 63;
    Qs[s] = q2[((size_t)b * LQ + q) * DIM + h * 64 + hd];
  }
  __syncthreads();
  int qr = tid >> 2, quad = tid & 3;
  float qreg[16];
#pragma unroll
  for (int j = 0; j < 16; ++j) qreg[j] = Qs[qr * 64 + quad * 16 + j];
  float m = -INFINITY, l = 0.f;
  float acc[16] = {};
  for (int kt = 0; kt < 8; ++kt) {
    __syncthreads();
    for (int s = tid; s < 4096; s += 256) {
      int kk = s >> 6, hd = s & 63;
      size_t src = ((size_t)b * LP + kt * 64 + kk) * DIM + h * 64 + hd;
      Ks[s] = kmat[src];
      Vs[s] = vmat[src];
    }
    __syncthreads();
    for (int kk = 0; kk < 64; ++kk) {
      float p = 0.f;
      const float* kr = &Ks[kk * 64 + quad * 16];
#pragma unroll
      for (int j = 0; j < 16; ++j) p = fmaf(qreg[j], kr[j], p);
      p += __shfl_xor(p, 1);
      p += __shfl_xor(p, 2);
      float sco = p * 8.0f;
      float nm = fmaxf(m, sco);
      float co = __expf(m - nm);
      float po = __expf(sco - nm);
      l = l * co + po;
      const float* vr = &Vs[kk * 64 + quad * 16];
#pragma unroll
      for (int j = 0; j < 16; ++j) acc[j] = fmaf(po, vr[j], acc[j] * co);
      m = nm;
    }
  }
  float inv = 1.0f / l;
  s16x8 vh0, vh1, vl0, vl1;
#pragma unroll
  for (int j = 0; j < 16; ++j) {
    float o = acc[j] * inv;
    unsigned short hh = f2bf(o);
    unsigned short ll = f2bf(o - bf2f(hh));
    if (j < 8) { vh0[j] = (short)hh; vl0[j] = (short)ll; }
    else       { vh1[j - 8] = (short)hh; vl1[j - 8] = (short)ll; }
  }
  size_t ob = ((size_t)b * LQ + qr) * DIM + h * 64 + quad * 16;
  *(s16x8*)(ath + ob) = vh0; *(s16x8*)(ath + ob + 8) = vh1;
  *(s16x8*)(atl + ob) = vl0; *(s16x8*)(atl + ob + 8) = vl1;
}

// ---------------------------------------------------------------------------
extern "C" void kernel_launch(void* const* d_in, const int* in_sizes, int n_in,
                              void* d_out, int out_size, void* d_ws,
                              size_t ws_size, hipStream_t stream) {
  const float* query = (const float*)d_in[0];
  const float* memory = (const float*)d_in[1];
  const float* Wq_c = (const float*)d_in[2];
  const float* Wk_c = (const float*)d_in[3];
  const float* Wv_c = (const float*)d_in[4];
  const float* Wq = (const float*)d_in[5];
  const float* Wk = (const float*)d_in[6];
  const float* Wv = (const float*)d_in[7];
  const float* Wp = (const float*)d_in[8];
  const float* bp = (const float*)d_in[9];
  float* out = (float*)d_out;
  float* ws = (float*)d_ws;

  // -------- workspace layout (float units) --------
  float* part = ws;  // [0, 1048576) — dead after k_mean; region reused:
  float* qlin = ws;                       // 262144 f32
  float* kclin = ws + 262144;             // 131072 f32
  float* q2 = ws + 393216;                // 262144 f32
  unsigned short* ath = (unsigned short*)(ws + 655360);   // 262144 bf16
  unsigned short* atl = (unsigned short*)(ws + 786432);   // 262144 bf16
  unsigned short* mmh = (unsigned short*)(ws + 1048576);  // 131072 bf16
  unsigned short* mml = (unsigned short*)(ws + 1114112);
  unsigned short* qh = (unsigned short*)(ws + 1179648);   // 262144 bf16
  unsigned short* ql = (unsigned short*)(ws + 1310720);
  unsigned short* WTh = (unsigned short*)(ws + 1441792);  // 6*262144 bf16
  unsigned short* WTl = (unsigned short*)(ws + 2228224);
  float* wsum = ws + 3014656;             // 2048 f32
  unsigned short* wth = (unsigned short*)(ws + 3016704);  // 8388608 bf16
  unsigned short* wtl = (unsigned short*)(ws + 7211008);  // 8388608 bf16
  // kmat/vmat overlay the (dead-after-stage1) weffT_hi region:
  float* kmat = ws + 3016704;             // 2097152 f32
  float* vmat = ws + 5113856;             // 2097152 f32
  unsigned short* mgh = (unsigned short*)(ws + 11405312); // 2097152 bf16
  unsigned short* mgl = (unsigned short*)(ws + 12453888);
  unsigned short* memh = (unsigned short*)(ws + 13502464); // 67108864 bf16
  unsigned short* meml = (unsigned short*)(ws + 47056896); // 67108864 bf16
  // total 80,611,328 floats = 322 MB

  // stage 1: mean over Lp (linearity) + pre-split memory to bf16 hi/lo
  k_part_split<<<2048, 256, 0, stream>>>(memory, part, memh, meml);
  k_mean_split<<<512, 256, 0, stream>>>(part, mmh, mml);

  // operand prep
  k_splitA<<<128, 256, 0, stream>>>(query, qh, ql);
  k_splitWT<<<dim3(8, 8, 6), 256, 0, stream>>>(Wq_c, Wk_c, Wq, Wk, Wv, Wp,
                                               WTh, WTl);

  // channel-attention projections (MFMA)
  mgemm<<<dim3(8, 8), 256, 0, stream>>>(qh, ql, WTh, WTl, nullptr, qlin, 512, 512);
  mgemm<<<dim3(4, 8), 256, 0, stream>>>(mmh, mml, WTh + 262144, WTl + 262144,
                                        nullptr, kclin, 512, 512);

  // channel softmax -> w_sum -> transposed split W_eff
  k_ch<<<64, 256, 0, stream>>>(qlin, kclin, wsum);
  k_weff<<<256, 256, 0, stream>>>(wsum, Wv_c, wth, wtl);

  // stage-1 aggregation GEMM (MFMA, K=2048) -> split magg
  k_stage1m<<<512, 256, 0, stream>>>(memh, meml, wth, wtl, mgh, mgl);

  // stage-2 projections (MFMA). NOTE: q2 written before kmat overlays weffT.
  mgemm<<<dim3(8, 8), 256, 0, stream>>>(qh, ql, WTh + 2 * 262144,
                                        WTl + 2 * 262144, nullptr, q2, 512, 512);
  mgemm<<<dim3(64, 8), 256, 0, stream>>>(mgh, mgl, WTh + 3 * 262144,
                                         WTl + 3 * 262144, nullptr, kmat, 512, 512);
  mgemm<<<dim3(64, 8), 256, 0, stream>>>(mgh, mgl, WTh + 4 * 262144,
                                         WTl + 4 * 262144, nullptr, vmat, 512, 512);

  // attention (f32) -> split attn, then output projection + bias (MFMA)
  k_attn<<<64, 256, 0, stream>>>(q2, kmat, vmat, ath, atl);
  mgemm<<<dim3(8, 8), 256, 0, stream>>>(ath, atl, WTh + 5 * 262144,
                                        WTl + 5 * 262144, bp, out, 512, 512);
}